// Round 3
// baseline (1508.684 us; speedup 1.0000x reference)
//
#include <hip/hip_runtime.h>

#define N_NODES 200000
#define N_EDGES 6400000
#define D_IN    128
#define D_HID   16
#define D_OUT   172
#define NB      3125      // buckets of 64 nodes: 3125*64 = 200000 exactly
#define NS1     800       // stage-1 blocks
#define EPB     8000      // edges per stage-1 block: 800*8000 = 6.4M exactly

// workspace offsets in 4-byte units (total 13,006,272 * 4B = 52.0 MB)
#define O_BTOT  0         // u32[3125]   per-bucket edge totals
#define O_BASE  3136      // u32[3126]   bucket base (exclusive scan of totals)
#define O_DINV  6272      // f32[200000] rsqrt(deg+1)
#define O_PACK  206272    // u32[6.4M]   bucket-sorted packed edges (ld<<24 | src)
#define O_CNT   6606272   // u32[800*3125] stage-1 counts (dead after k_scatter)
#define O_BUFA  6606272   // f32[3.2M]   lin1 / agg2  (aliases O_CNT - counts dead)
#define O_BUFB  9806272   // f32[3.2M]   h

// ---------------------------------------------------------------------------
// S1: per-block LDS histogram of dst>>6 -> counts[block][bucket]
__global__ __launch_bounds__(256) void k_hist(const int* __restrict__ dst,
                                              unsigned* __restrict__ counts) {
    __shared__ unsigned cnt[NB];   // 12.5 KB
    for (int i = threadIdx.x; i < NB; i += 256) cnt[i] = 0;
    __syncthreads();
    const int* dp = dst + blockIdx.x * EPB;
    for (int i = threadIdx.x; i < EPB; i += 256)
        atomicAdd(&cnt[dp[i] >> 6], 1u);
    __syncthreads();
    unsigned* out = counts + (size_t)blockIdx.x * NB;
    for (int i = threadIdx.x; i < NB; i += 256) out[i] = cnt[i];
}

// S2: per-column exclusive scan of counts (in place) + column totals
__global__ __launch_bounds__(256) void k_scan_col(unsigned* __restrict__ counts,
                                                  unsigned* __restrict__ btot) {
    __shared__ unsigned arr[NS1];  // 3.2 KB
    int b = blockIdx.x;
    for (int i = threadIdx.x; i < NS1; i += 256)
        arr[i] = counts[(size_t)i * NB + b];
    __syncthreads();
    if (threadIdx.x < 64) {
        int l = threadIdx.x;
        int lo = l * 13, hi = min(lo + 13, NS1);   // 13*64 = 832 >= 800
        unsigned sum = 0;
        for (int i = lo; i < hi; ++i) sum += arr[i];
        unsigned incl = sum;
#pragma unroll
        for (int o = 1; o < 64; o <<= 1) {
            unsigned tmp = __shfl_up(incl, o);
            if (l >= o) incl += tmp;
        }
        if (l == 63) btot[b] = incl;               // column total
        unsigned run = incl - sum;                 // exclusive base for this lane
        for (int i = lo; i < hi; ++i) { unsigned v = arr[i]; arr[i] = run; run += v; }
    }
    __syncthreads();
    for (int i = threadIdx.x; i < NS1; i += 256)
        counts[(size_t)i * NB + b] = arr[i];
}

// S2b: exclusive scan of the 3125 bucket totals -> base[3126]
__global__ __launch_bounds__(64) void k_scan_base(const unsigned* __restrict__ btot,
                                                  unsigned* __restrict__ base) {
    int l = threadIdx.x;
    int lo = l * 49, hi = min(lo + 49, NB);        // 49*64 = 3136 >= 3125
    unsigned sum = 0;
    for (int i = lo; i < hi; ++i) sum += btot[i];
    unsigned incl = sum;
#pragma unroll
    for (int o = 1; o < 64; o <<= 1) {
        unsigned tmp = __shfl_up(incl, o);
        if (l >= o) incl += tmp;
    }
    unsigned run = incl - sum;
    for (int i = lo; i < hi; ++i) { unsigned v = btot[i]; base[i] = run; run += v; }
    if (l == 63) base[NB] = incl;                  // = N_EDGES
}

// S3: scatter edges to bucket-sorted order, packed (ld<<24 | src), LDS offsets
__global__ __launch_bounds__(256) void k_scatter(const int* __restrict__ src,
                                                 const int* __restrict__ dst,
                                                 const unsigned* __restrict__ counts,
                                                 const unsigned* __restrict__ base,
                                                 unsigned* __restrict__ packed) {
    __shared__ unsigned off[NB];   // 12.5 KB
    const unsigned* crow = counts + (size_t)blockIdx.x * NB;
    for (int i = threadIdx.x; i < NB; i += 256) off[i] = base[i] + crow[i];
    __syncthreads();
    const int* sp = src + blockIdx.x * EPB;
    const int* dp = dst + blockIdx.x * EPB;
    for (int i = threadIdx.x; i < EPB; i += 256) {
        int s = sp[i], d = dp[i];
        unsigned slot = atomicAdd(&off[d >> 6], 1u);
        packed[slot] = ((unsigned)(d & 63) << 24) | (unsigned)s;
    }
}

// S4: per-bucket degree histogram -> dinv = rsqrt(deg+1)
__global__ __launch_bounds__(256) void k_dinvk(const unsigned* __restrict__ packed,
                                               const unsigned* __restrict__ base,
                                               float* __restrict__ dinv) {
    __shared__ unsigned cnt[64];
    if (threadIdx.x < 64) cnt[threadIdx.x] = 0;
    __syncthreads();
    int b = blockIdx.x;
    unsigned beg = base[b], end = base[b + 1];
    for (unsigned i = beg + threadIdx.x; i < end; i += 256)
        atomicAdd(&cnt[packed[i] >> 24], 1u);
    __syncthreads();
    if (threadIdx.x < 64)
        dinv[b * 64 + threadIdx.x] = rsqrtf((float)(cnt[threadIdx.x] + 1));
}

// ---------------------------------------------------------------------------
// lin = x @ W1  [N,128]x[128,16] -> [N,16]. 256 thr = 64 nodes x 4 k-chunks.
__global__ __launch_bounds__(256) void k_lin1(const float* __restrict__ x,
                                              const float* __restrict__ W1,
                                              float* __restrict__ lin) {
    __shared__ float sW[D_IN * D_HID];  // 8 KB, [k][j]
    for (int t = threadIdx.x; t < D_IN * D_HID; t += 256) sW[t] = W1[t];
    __syncthreads();

    int g  = threadIdx.x & 3;
    int nl = threadIdx.x >> 2;
    int n  = blockIdx.x * 64 + nl;   // grid exact: 3125*64

    float acc[16];
#pragma unroll
    for (int j = 0; j < 16; ++j) acc[j] = 0.f;

    const float4* xr = (const float4*)(x + (size_t)n * D_IN + g * 32);
#pragma unroll
    for (int i = 0; i < 8; ++i) {
        float4 xv = xr[i];
        int k = g * 32 + i * 4;
#pragma unroll
        for (int j = 0; j < 16; ++j) {
            acc[j] += xv.x * sW[(k + 0) * 16 + j] + xv.y * sW[(k + 1) * 16 + j]
                    + xv.z * sW[(k + 2) * 16 + j] + xv.w * sW[(k + 3) * 16 + j];
        }
    }
#pragma unroll
    for (int j = 0; j < 16; ++j) {
        acc[j] += __shfl_xor(acc[j], 1);
        acc[j] += __shfl_xor(acc[j], 2);
    }
    float4 o;
    o.x = acc[g * 4 + 0]; o.y = acc[g * 4 + 1];
    o.z = acc[g * 4 + 2]; o.w = acc[g * 4 + 3];
    *(float4*)(lin + (size_t)n * 16 + g * 4) = o;
}

// ---------------------------------------------------------------------------
// fused pull-aggregation: one block per bucket, acc[64][16] in LDS.
// agg[n] = fin[n]*dinv[n]^2 + sum_{s->n} fin[s]*dinv[s]*dinv[n]
// RELU epilogue: out = relu(acc + bias)
template <bool RELU>
__global__ __launch_bounds__(256) void k_agg(const unsigned* __restrict__ packed,
                                             const unsigned* __restrict__ base,
                                             const float* __restrict__ dinv,
                                             const float* __restrict__ fin,
                                             const float* __restrict__ bias,
                                             float* __restrict__ out) {
    __shared__ float    acc[64 * 16];   // 4 KB
    __shared__ float    sdinv[64];
    __shared__ unsigned epk[256];
    __shared__ float    wbuf[256];
    int t = threadIdx.x, b = blockIdx.x;
    if (t < 64) sdinv[t] = dinv[b * 64 + t];
    __syncthreads();
    // self-loop init: acc[l] = fin[b*1024+l] * dinv[node]^2  (contiguous reads)
    for (int l = t; l < 1024; l += 256) {
        float dv = sdinv[l >> 4];
        acc[l] = fin[(size_t)b * 1024 + l] * dv * dv;
    }
    unsigned beg = base[b], end = base[b + 1];
    int g = t >> 4, j = t & 15;
    for (unsigned c0 = beg; c0 < end; c0 += 256) {
        int m = (int)min(256u, end - c0);
        __syncthreads();                   // protects acc init / epk reuse
        if (t < m) {
            unsigned p = packed[c0 + t];
            epk[t]  = p;
            wbuf[t] = dinv[p & 0x3FFFFu] * sdinv[p >> 24];  // per-edge weight once
        }
        __syncthreads();
#pragma unroll 4
        for (int i = g; i < m; i += 16) {
            unsigned p = epk[i];           // LDS broadcast within 16-lane group
            int s = (int)(p & 0x3FFFFu);
            atomicAdd(&acc[(p >> 24) * 16 + j], fin[(size_t)s * 16 + j] * wbuf[i]);
        }
    }
    __syncthreads();
    float bb = RELU ? bias[t & 15] : 0.f;  // (t+r*256)&15 == t&15
    for (int l = t; l < 1024; l += 256) {
        float v = acc[l];
        if (RELU) v = fmaxf(v + bb, 0.f);
        out[(size_t)b * 1024 + l] = v;
    }
}

// ---------------------------------------------------------------------------
// logits = agg2 @ W2 + b2; out = log_softmax(logits). One wave per node.
__global__ __launch_bounds__(256) void k_out(const float* __restrict__ agg2,
                                             const float* __restrict__ W2,
                                             const float* __restrict__ b2,
                                             float* __restrict__ out) {
    __shared__ float sW[D_HID * D_OUT];
    __shared__ float sb[D_OUT];
    for (int t = threadIdx.x; t < D_HID * D_OUT; t += 256) sW[t] = W2[t];
    for (int t = threadIdx.x; t < D_OUT; t += 256) sb[t] = b2[t];
    __syncthreads();

    int wid = threadIdx.x >> 6, lane = threadIdx.x & 63;
    int n = blockIdx.x * 4 + wid;    // grid exact: 50000*4
    const float4* ar = (const float4*)(agg2 + (size_t)n * 16);
    float4 a0 = ar[0], a1 = ar[1], a2 = ar[2], a3 = ar[3];
    float a[16] = {a0.x, a0.y, a0.z, a0.w, a1.x, a1.y, a1.z, a1.w,
                   a2.x, a2.y, a2.z, a2.w, a3.x, a3.y, a3.z, a3.w};

    bool has2 = (lane < D_OUT - 128);
    int  c2   = has2 ? lane + 128 : 0;
    float l0 = sb[lane], l1 = sb[lane + 64];
    float l2 = has2 ? sb[c2] : -INFINITY;
#pragma unroll
    for (int k = 0; k < 16; ++k) {
        float av = a[k];
        l0 += av * sW[k * D_OUT + lane];
        l1 += av * sW[k * D_OUT + lane + 64];
        l2 += av * sW[k * D_OUT + c2];
    }
    float m = fmaxf(fmaxf(l0, l1), l2);
#pragma unroll
    for (int o = 1; o < 64; o <<= 1) m = fmaxf(m, __shfl_xor(m, o));
    float e0 = __expf(l0 - m), e1 = __expf(l1 - m);
    float e2 = has2 ? __expf(l2 - m) : 0.f;
    float s = e0 + e1 + e2;
#pragma unroll
    for (int o = 1; o < 64; o <<= 1) s += __shfl_xor(s, o);
    float ls = m + __logf(s);
    float* op = out + (size_t)n * D_OUT;
    op[lane]      = l0 - ls;
    op[lane + 64] = l1 - ls;
    if (has2) op[lane + 128] = l2 - ls;
}

// ---------------------------------------------------------------------------
extern "C" void kernel_launch(void* const* d_in, const int* in_sizes, int n_in,
                              void* d_out, int out_size, void* d_ws, size_t ws_size,
                              hipStream_t stream) {
    const float* x     = (const float*)d_in[0];
    const int*   edges = (const int*)d_in[1];   // [2, N_EDGES]
    const float* W1    = (const float*)d_in[2];
    const float* b1    = (const float*)d_in[3];
    const float* W2    = (const float*)d_in[4];
    const float* b2    = (const float*)d_in[5];
    float*       out   = (float*)d_out;

    const int* src = edges;
    const int* dst = edges + N_EDGES;

    unsigned* ws     = (unsigned*)d_ws;
    unsigned* btot   = ws + O_BTOT;
    unsigned* base   = ws + O_BASE;
    float*    dinv   = (float*)(ws + O_DINV);
    unsigned* packed = ws + O_PACK;
    unsigned* counts = ws + O_CNT;              // dead after k_scatter
    float*    bufA   = (float*)(ws + O_BUFA);   // aliases counts
    float*    bufB   = (float*)(ws + O_BUFB);

    // --- bucket-sort CSR build: zero global atomics ---
    k_hist     <<<NS1, 256, 0, stream>>>(dst, counts);
    k_scan_col <<<NB,  256, 0, stream>>>(counts, btot);
    k_scan_base<<<1,    64, 0, stream>>>(btot, base);
    k_scatter  <<<NS1, 256, 0, stream>>>(src, dst, counts, base, packed);
    k_dinvk    <<<NB,  256, 0, stream>>>(packed, base, dinv);

    // --- layer 1: project 128->16, aggregate (relu+bias fused) ---
    k_lin1      <<<NB, 256, 0, stream>>>(x, W1, bufA);
    k_agg<true> <<<NB, 256, 0, stream>>>(packed, base, dinv, bufA, b1, bufB);

    // --- layer 2 (reassociated): aggregate h, then 16->172 + log_softmax ---
    k_agg<false><<<NB, 256, 0, stream>>>(packed, base, dinv, bufB, b1, bufA);
    k_out       <<<N_NODES / 4, 256, 0, stream>>>(bufA, W2, b2, out);
}

// Round 4
// 525.583 us; speedup vs baseline: 2.8705x; 2.8705x over previous
//
#include <hip/hip_runtime.h>

#define N_NODES 200000
#define N_EDGES 6400000
#define D_IN    128
#define D_HID   16
#define D_OUT   172

#define NS1     800       // stage-1 blocks
#define EPB     8000      // edges per stage-1 block: 800*8000 = 6.4M exactly
#define SBN     98        // superbuckets of 2048 nodes: 98*2048 >= 200000
#define SB_NODES 2048

// workspace offsets in 4-byte words (total 13,278,784 words = 53.1 MB)
#define O_BTOT  0          // u32[98]    per-SB edge totals
#define O_BASE  128        // u32[99]    SB base (exclusive scan)
#define O_CNT1  256        // u32[800*98] stage-1 counts
#define O_ROW   78656      // int[200001] CSR rowptr
#define O_DINV  278784     // f32[200000] rsqrt(deg+1)
#define O_COL   478784     // int[6.4M]  CSR column (src) ids
#define O_PACK  6878784    // u32[6.4M]  SB-sorted packed edges (dead after k_csr)
#define O_BUFA  6878784    // f32[3.2M]  lin1' / agg2   (aliases PACK low half)
#define O_BUFB  10078784   // f32[3.2M]  h'             (aliases PACK high half)

// ---------------------------------------------------------------------------
// S1: per-block LDS histogram of dst>>11 -> counts[block][sb]
__global__ __launch_bounds__(256) void k_hist1(const int* __restrict__ dst,
                                               unsigned* __restrict__ counts) {
    __shared__ unsigned cnt[SBN];
    for (int i = threadIdx.x; i < SBN; i += 256) cnt[i] = 0;
    __syncthreads();
    const int* dp = dst + blockIdx.x * EPB;
    for (int i = threadIdx.x; i < EPB; i += 256)
        atomicAdd(&cnt[dp[i] >> 11], 1u);
    __syncthreads();
    unsigned* out = counts + (size_t)blockIdx.x * SBN;
    for (int i = threadIdx.x; i < SBN; i += 256) out[i] = cnt[i];
}

// S2: per-column exclusive scan of counts (in place) + column totals
__global__ __launch_bounds__(256) void k_scan_col(unsigned* __restrict__ counts,
                                                  unsigned* __restrict__ btot) {
    __shared__ unsigned arr[NS1];
    int b = blockIdx.x;
    for (int i = threadIdx.x; i < NS1; i += 256)
        arr[i] = counts[(size_t)i * SBN + b];
    __syncthreads();
    if (threadIdx.x < 64) {
        int l = threadIdx.x;
        int lo = l * 13, hi = min(lo + 13, NS1);   // 13*64 = 832 >= 800
        unsigned sum = 0;
        for (int i = lo; i < hi; ++i) sum += arr[i];
        unsigned incl = sum;
#pragma unroll
        for (int o = 1; o < 64; o <<= 1) {
            unsigned tmp = __shfl_up(incl, o);
            if (l >= o) incl += tmp;
        }
        if (l == 63) btot[b] = incl;
        unsigned run = incl - sum;
        for (int i = lo; i < hi; ++i) { unsigned v = arr[i]; arr[i] = run; run += v; }
    }
    __syncthreads();
    for (int i = threadIdx.x; i < NS1; i += 256)
        counts[(size_t)i * SBN + b] = arr[i];
}

// S2b: exclusive scan of the 98 SB totals -> base[99]
__global__ __launch_bounds__(64) void k_scan_base(const unsigned* __restrict__ btot,
                                                  unsigned* __restrict__ base) {
    int l = threadIdx.x;
    int lo = l * 2, hi = min(lo + 2, SBN);
    unsigned sum = 0;
    for (int i = lo; i < hi; ++i) sum += btot[i];
    unsigned incl = sum;
#pragma unroll
    for (int o = 1; o < 64; o <<= 1) {
        unsigned tmp = __shfl_up(incl, o);
        if (l >= o) incl += tmp;
    }
    unsigned run = incl - sum;
    for (int i = lo; i < hi; ++i) { unsigned v = btot[i]; base[i] = run; run += v; }
    if (l == 63) base[SBN] = incl;                  // = N_EDGES
}

// S3: scatter edges into SB-sorted order, packed (local_dst<<18 | src).
// Per-(block,SB) dest runs avg 82 edges (~326 B) -> decent write coalescing.
__global__ __launch_bounds__(256) void k_scatter1(const int* __restrict__ src,
                                                  const int* __restrict__ dst,
                                                  const unsigned* __restrict__ counts,
                                                  const unsigned* __restrict__ base,
                                                  unsigned* __restrict__ packed) {
    __shared__ unsigned off[SBN];
    const unsigned* crow = counts + (size_t)blockIdx.x * SBN;
    for (int i = threadIdx.x; i < SBN; i += 256) off[i] = base[i] + crow[i];
    __syncthreads();
    const int* sp = src + blockIdx.x * EPB;
    const int* dp = dst + blockIdx.x * EPB;
    for (int i = threadIdx.x; i < EPB; i += 256) {
        int s = sp[i], d = dp[i];
        unsigned slot = atomicAdd(&off[d >> 11], 1u);
        packed[slot] = ((unsigned)(d & (SB_NODES - 1)) << 18) | (unsigned)s;
    }
}

// S4: one block per SB -> full CSR (rowptr, col) + dinv. All LDS-local.
__global__ __launch_bounds__(1024) void k_csr(const unsigned* __restrict__ packed,
                                              const unsigned* __restrict__ base,
                                              int* __restrict__ rowptr,
                                              float* __restrict__ dinv,
                                              int* __restrict__ col) {
    __shared__ unsigned cnt[SB_NODES];
    __shared__ unsigned off[SB_NODES];
    __shared__ unsigned wsum[16];
    int t = threadIdx.x, sb = blockIdx.x;
    unsigned beg = base[sb], end = base[sb + 1];
    cnt[t] = 0; cnt[t + 1024] = 0;
    __syncthreads();
    for (unsigned i = beg + t; i < end; i += 1024)
        atomicAdd(&cnt[packed[i] >> 18], 1u);
    __syncthreads();
    // exclusive scan of 2048 counts: thread t owns entries 2t, 2t+1
    unsigned e0 = cnt[2 * t], e1 = cnt[2 * t + 1], s = e0 + e1;
    int lane = t & 63, wid = t >> 6;
    unsigned incl = s;
#pragma unroll
    for (int o = 1; o < 64; o <<= 1) {
        unsigned tmp = __shfl_up(incl, o);
        if (lane >= o) incl += tmp;
    }
    if (lane == 63) wsum[wid] = incl;
    __syncthreads();
    unsigned wbase = 0;
    for (int w = 0; w < wid; ++w) wbase += wsum[w];
    unsigned ex = wbase + incl - s;          // exclusive base for entry 2t
    off[2 * t]     = ex;
    off[2 * t + 1] = ex + e0;
    int n0 = sb * SB_NODES + 2 * t;
    if (n0     <= N_NODES) rowptr[n0]     = (int)(beg + ex);
    if (n0 + 1 <= N_NODES) rowptr[n0 + 1] = (int)(beg + ex + e0);
    if (n0     <  N_NODES) dinv[n0]       = rsqrtf((float)(e0 + 1));
    if (n0 + 1 <  N_NODES) dinv[n0 + 1]   = rsqrtf((float)(e1 + 1));
    __syncthreads();
    // pass 2: place src ids at CSR slots (writes stay in [beg,end): ~520 KB)
    for (unsigned i = beg + t; i < end; i += 1024) {
        unsigned p = packed[i];
        unsigned slot = atomicAdd(&off[p >> 18], 1u);
        col[beg + slot] = (int)(p & 0x3FFFFu);
    }
}

// ---------------------------------------------------------------------------
// lin' = (x @ W1) * dinv[n]  (pre-scaled for weight-folded aggregation)
__global__ __launch_bounds__(256) void k_lin1(const float* __restrict__ x,
                                              const float* __restrict__ W1,
                                              const float* __restrict__ dinv,
                                              float* __restrict__ lin) {
    __shared__ float sW[D_IN * D_HID];
    for (int t = threadIdx.x; t < D_IN * D_HID; t += 256) sW[t] = W1[t];
    __syncthreads();

    int g  = threadIdx.x & 3;
    int nl = threadIdx.x >> 2;
    int n  = blockIdx.x * 64 + nl;   // grid exact: 3125*64

    float acc[16];
#pragma unroll
    for (int j = 0; j < 16; ++j) acc[j] = 0.f;

    const float4* xr = (const float4*)(x + (size_t)n * D_IN + g * 32);
#pragma unroll
    for (int i = 0; i < 8; ++i) {
        float4 xv = xr[i];
        int k = g * 32 + i * 4;
#pragma unroll
        for (int j = 0; j < 16; ++j) {
            acc[j] += xv.x * sW[(k + 0) * 16 + j] + xv.y * sW[(k + 1) * 16 + j]
                    + xv.z * sW[(k + 2) * 16 + j] + xv.w * sW[(k + 3) * 16 + j];
        }
    }
#pragma unroll
    for (int j = 0; j < 16; ++j) {
        acc[j] += __shfl_xor(acc[j], 1);
        acc[j] += __shfl_xor(acc[j], 2);
    }
    float di = dinv[n];
    float4 o;
    o.x = acc[g * 4 + 0] * di; o.y = acc[g * 4 + 1] * di;
    o.z = acc[g * 4 + 2] * di; o.w = acc[g * 4 + 3] * di;
    *(float4*)(lin + (size_t)n * 16 + g * 4) = o;
}

// ---------------------------------------------------------------------------
// pull-gather, weight-folded: acc = fin'[n] + sum fin'[col[i]]; v = dd*acc.
// MODE 1: v = relu(v + b1) * dd  (pre-scale for next layer).  MODE 0: plain.
// 16 lanes per node; 8 independent accumulators for memory-level parallelism.
template <int MODE>
__global__ __launch_bounds__(256) void k_gather(const int* __restrict__ rowptr,
                                                const int* __restrict__ col,
                                                const float* __restrict__ dinv,
                                                const float* __restrict__ fin,
                                                const float* __restrict__ bias,
                                                float* __restrict__ out) {
    int t = threadIdx.x;
    int n = blockIdx.x * 16 + (t >> 4);   // grid exact: 12500*16
    int lane = t & 15;
    int beg = rowptr[n], end = rowptr[n + 1];
    float a0 = fin[n * 16 + lane];        // self loop (pre-scaled)
    float a1 = 0.f, a2 = 0.f, a3 = 0.f, a4 = 0.f, a5 = 0.f, a6 = 0.f, a7 = 0.f;
    int i = beg;
    for (; i + 8 <= end; i += 8) {
        int s0 = col[i + 0], s1 = col[i + 1], s2 = col[i + 2], s3 = col[i + 3];
        int s4 = col[i + 4], s5 = col[i + 5], s6 = col[i + 6], s7 = col[i + 7];
        float f0 = fin[s0 * 16 + lane], f1 = fin[s1 * 16 + lane];
        float f2 = fin[s2 * 16 + lane], f3 = fin[s3 * 16 + lane];
        float f4 = fin[s4 * 16 + lane], f5 = fin[s5 * 16 + lane];
        float f6 = fin[s6 * 16 + lane], f7 = fin[s7 * 16 + lane];
        a0 += f0; a1 += f1; a2 += f2; a3 += f3;
        a4 += f4; a5 += f5; a6 += f6; a7 += f7;
    }
    for (; i < end; ++i) a0 += fin[col[i] * 16 + lane];
    float acc = ((a0 + a1) + (a2 + a3)) + ((a4 + a5) + (a6 + a7));
    float dd = dinv[n];
    float v = acc * dd;
    if (MODE) v = fmaxf(v + bias[lane], 0.f) * dd;
    out[n * 16 + lane] = v;
}

// ---------------------------------------------------------------------------
// logits = agg2 @ W2 + b2; out = log_softmax(logits). One wave per node.
__global__ __launch_bounds__(256) void k_out(const float* __restrict__ agg2,
                                             const float* __restrict__ W2,
                                             const float* __restrict__ b2,
                                             float* __restrict__ out) {
    __shared__ float sW[D_HID * D_OUT];
    __shared__ float sb[D_OUT];
    for (int t = threadIdx.x; t < D_HID * D_OUT; t += 256) sW[t] = W2[t];
    for (int t = threadIdx.x; t < D_OUT; t += 256) sb[t] = b2[t];
    __syncthreads();

    int wid = threadIdx.x >> 6, lane = threadIdx.x & 63;
    int n = blockIdx.x * 4 + wid;    // grid exact: 50000*4
    const float4* ar = (const float4*)(agg2 + (size_t)n * 16);
    float4 a0 = ar[0], a1 = ar[1], a2 = ar[2], a3 = ar[3];
    float a[16] = {a0.x, a0.y, a0.z, a0.w, a1.x, a1.y, a1.z, a1.w,
                   a2.x, a2.y, a2.z, a2.w, a3.x, a3.y, a3.z, a3.w};

    bool has2 = (lane < D_OUT - 128);
    int  c2   = has2 ? lane + 128 : 0;
    float l0 = sb[lane], l1 = sb[lane + 64];
    float l2 = has2 ? sb[c2] : -INFINITY;
#pragma unroll
    for (int k = 0; k < 16; ++k) {
        float av = a[k];
        l0 += av * sW[k * D_OUT + lane];
        l1 += av * sW[k * D_OUT + lane + 64];
        l2 += av * sW[k * D_OUT + c2];
    }
    float m = fmaxf(fmaxf(l0, l1), l2);
#pragma unroll
    for (int o = 1; o < 64; o <<= 1) m = fmaxf(m, __shfl_xor(m, o));
    float e0 = __expf(l0 - m), e1 = __expf(l1 - m);
    float e2 = has2 ? __expf(l2 - m) : 0.f;
    float s = e0 + e1 + e2;
#pragma unroll
    for (int o = 1; o < 64; o <<= 1) s += __shfl_xor(s, o);
    float ls = m + __logf(s);
    float* op = out + (size_t)n * D_OUT;
    op[lane]      = l0 - ls;
    op[lane + 64] = l1 - ls;
    if (has2) op[lane + 128] = l2 - ls;
}

// ---------------------------------------------------------------------------
extern "C" void kernel_launch(void* const* d_in, const int* in_sizes, int n_in,
                              void* d_out, int out_size, void* d_ws, size_t ws_size,
                              hipStream_t stream) {
    const float* x     = (const float*)d_in[0];
    const int*   edges = (const int*)d_in[1];   // [2, N_EDGES]
    const float* W1    = (const float*)d_in[2];
    const float* b1    = (const float*)d_in[3];
    const float* W2    = (const float*)d_in[4];
    const float* b2    = (const float*)d_in[5];
    float*       out   = (float*)d_out;

    const int* src = edges;
    const int* dst = edges + N_EDGES;

    unsigned* ws     = (unsigned*)d_ws;
    unsigned* btot   = ws + O_BTOT;
    unsigned* base   = ws + O_BASE;
    unsigned* counts = ws + O_CNT1;
    int*      rowptr = (int*)(ws + O_ROW);
    float*    dinv   = (float*)(ws + O_DINV);
    int*      col    = (int*)(ws + O_COL);
    unsigned* packed = ws + O_PACK;             // dead after k_csr
    float*    bufA   = (float*)(ws + O_BUFA);   // aliases packed
    float*    bufB   = (float*)(ws + O_BUFB);   // aliases packed

    // --- CSR build: zero global atomics, localized writes ---
    k_hist1    <<<NS1, 256, 0, stream>>>(dst, counts);
    k_scan_col <<<SBN, 256, 0, stream>>>(counts, btot);
    k_scan_base<<<1,    64, 0, stream>>>(btot, base);
    k_scatter1 <<<NS1, 256, 0, stream>>>(src, dst, counts, base, packed);
    k_csr      <<<SBN, 1024, 0, stream>>>(packed, base, rowptr, dinv, col);

    // --- layer 1: project 128->16 (pre-scaled), gather (relu+bias+prescale) ---
    k_lin1     <<<N_NODES / 64, 256, 0, stream>>>(x, W1, dinv, bufA);
    k_gather<1><<<N_NODES / 16, 256, 0, stream>>>(rowptr, col, dinv, bufA, b1, bufB);

    // --- layer 2 (reassociated): gather h', then 16->172 + log_softmax ---
    k_gather<0><<<N_NODES / 16, 256, 0, stream>>>(rowptr, col, dinv, bufB, b1, bufA);
    k_out      <<<N_NODES / 4, 256, 0, stream>>>(bufA, W2, b2, out);
}

// Round 5
// 446.956 us; speedup vs baseline: 3.3755x; 1.1759x over previous
//
#include <hip/hip_runtime.h>
#include <hip/hip_fp16.h>

#define N_NODES 200000
#define N_EDGES 6400000
#define D_IN    128
#define D_HID   16
#define D_OUT   172

#define NS1     800       // stage-1 blocks
#define EPB     8000      // edges per stage-1 block: 800*8000 = 6.4M exactly
#define SBN     98        // superbuckets of 2048 nodes: 98*2048 >= 200000
#define SB_NODES 2048

// workspace offsets in 4-byte words (total 13,278,784 words = 53.1 MB)
#define O_BTOT  0          // u32[98]    per-SB edge totals
#define O_BASE  128        // u32[99]    SB base (exclusive scan)
#define O_CNT1  256        // u32[800*98] stage-1 counts
#define O_ROW   78656      // int[200001] CSR rowptr
#define O_DINV  278784     // f32[200000] rsqrt(deg+1)
#define O_COL   478784     // int[6.4M]  CSR column (src) ids
#define O_PACK  6878784    // u32[6.4M]  SB-sorted packed edges (dead after k_csr)
#define O_F16A  6878784    // f16[3.2M]  lin1'  (aliases PACK, 1.6M words)
#define O_F16B  8478784    // f16[3.2M]  h'     (1.6M words)
#define O_AGG2  10078784   // f32[3.2M]  agg2

// ---------------------------------------------------------------------------
// S1: per-block LDS histogram of dst>>11 -> counts[block][sb]
__global__ __launch_bounds__(256) void k_hist1(const int* __restrict__ dst,
                                               unsigned* __restrict__ counts) {
    __shared__ unsigned cnt[SBN];
    for (int i = threadIdx.x; i < SBN; i += 256) cnt[i] = 0;
    __syncthreads();
    const int* dp = dst + blockIdx.x * EPB;
    for (int i = threadIdx.x; i < EPB; i += 256)
        atomicAdd(&cnt[dp[i] >> 11], 1u);
    __syncthreads();
    unsigned* out = counts + (size_t)blockIdx.x * SBN;
    for (int i = threadIdx.x; i < SBN; i += 256) out[i] = cnt[i];
}

// S2: per-column exclusive scan of counts (in place) + column totals
__global__ __launch_bounds__(256) void k_scan_col(unsigned* __restrict__ counts,
                                                  unsigned* __restrict__ btot) {
    __shared__ unsigned arr[NS1];
    int b = blockIdx.x;
    for (int i = threadIdx.x; i < NS1; i += 256)
        arr[i] = counts[(size_t)i * SBN + b];
    __syncthreads();
    if (threadIdx.x < 64) {
        int l = threadIdx.x;
        int lo = l * 13, hi = min(lo + 13, NS1);   // 13*64 = 832 >= 800
        unsigned sum = 0;
        for (int i = lo; i < hi; ++i) sum += arr[i];
        unsigned incl = sum;
#pragma unroll
        for (int o = 1; o < 64; o <<= 1) {
            unsigned tmp = __shfl_up(incl, o);
            if (l >= o) incl += tmp;
        }
        if (l == 63) btot[b] = incl;
        unsigned run = incl - sum;
        for (int i = lo; i < hi; ++i) { unsigned v = arr[i]; arr[i] = run; run += v; }
    }
    __syncthreads();
    for (int i = threadIdx.x; i < NS1; i += 256)
        counts[(size_t)i * SBN + b] = arr[i];
}

// S2b: exclusive scan of the 98 SB totals -> base[99]
__global__ __launch_bounds__(64) void k_scan_base(const unsigned* __restrict__ btot,
                                                  unsigned* __restrict__ base) {
    int l = threadIdx.x;
    int lo = l * 2, hi = min(lo + 2, SBN);
    unsigned sum = 0;
    for (int i = lo; i < hi; ++i) sum += btot[i];
    unsigned incl = sum;
#pragma unroll
    for (int o = 1; o < 64; o <<= 1) {
        unsigned tmp = __shfl_up(incl, o);
        if (l >= o) incl += tmp;
    }
    unsigned run = incl - sum;
    for (int i = lo; i < hi; ++i) { unsigned v = btot[i]; base[i] = run; run += v; }
    if (l == 63) base[SBN] = incl;                  // = N_EDGES
}

// S3: scatter edges into SB-sorted order, packed (local_dst<<18 | src).
__global__ __launch_bounds__(256) void k_scatter1(const int* __restrict__ src,
                                                  const int* __restrict__ dst,
                                                  const unsigned* __restrict__ counts,
                                                  const unsigned* __restrict__ base,
                                                  unsigned* __restrict__ packed) {
    __shared__ unsigned off[SBN];
    const unsigned* crow = counts + (size_t)blockIdx.x * SBN;
    for (int i = threadIdx.x; i < SBN; i += 256) off[i] = base[i] + crow[i];
    __syncthreads();
    const int* sp = src + blockIdx.x * EPB;
    const int* dp = dst + blockIdx.x * EPB;
    for (int i = threadIdx.x; i < EPB; i += 256) {
        int s = sp[i], d = dp[i];
        unsigned slot = atomicAdd(&off[d >> 11], 1u);
        packed[slot] = ((unsigned)(d & (SB_NODES - 1)) << 18) | (unsigned)s;
    }
}

// S4: one block per SB -> full CSR (rowptr, col) + dinv. All LDS-local.
__global__ __launch_bounds__(1024) void k_csr(const unsigned* __restrict__ packed,
                                              const unsigned* __restrict__ base,
                                              int* __restrict__ rowptr,
                                              float* __restrict__ dinv,
                                              int* __restrict__ col) {
    __shared__ unsigned cnt[SB_NODES];
    __shared__ unsigned off[SB_NODES];
    __shared__ unsigned wsum[16];
    int t = threadIdx.x, sb = blockIdx.x;
    unsigned beg = base[sb], end = base[sb + 1];
    cnt[t] = 0; cnt[t + 1024] = 0;
    __syncthreads();
    for (unsigned i = beg + t; i < end; i += 1024)
        atomicAdd(&cnt[packed[i] >> 18], 1u);
    __syncthreads();
    unsigned e0 = cnt[2 * t], e1 = cnt[2 * t + 1], s = e0 + e1;
    int lane = t & 63, wid = t >> 6;
    unsigned incl = s;
#pragma unroll
    for (int o = 1; o < 64; o <<= 1) {
        unsigned tmp = __shfl_up(incl, o);
        if (lane >= o) incl += tmp;
    }
    if (lane == 63) wsum[wid] = incl;
    __syncthreads();
    unsigned wbase = 0;
    for (int w = 0; w < wid; ++w) wbase += wsum[w];
    unsigned ex = wbase + incl - s;
    off[2 * t]     = ex;
    off[2 * t + 1] = ex + e0;
    int n0 = sb * SB_NODES + 2 * t;
    if (n0     <= N_NODES) rowptr[n0]     = (int)(beg + ex);
    if (n0 + 1 <= N_NODES) rowptr[n0 + 1] = (int)(beg + ex + e0);
    if (n0     <  N_NODES) dinv[n0]       = rsqrtf((float)(e0 + 1));
    if (n0 + 1 <  N_NODES) dinv[n0 + 1]   = rsqrtf((float)(e1 + 1));
    __syncthreads();
    for (unsigned i = beg + t; i < end; i += 1024) {
        unsigned p = packed[i];
        unsigned slot = atomicAdd(&off[p >> 18], 1u);
        col[beg + slot] = (int)(p & 0x3FFFFu);
    }
}

// ---------------------------------------------------------------------------
// lin' = (x @ W1) * dinv[n], stored fp16 (gathers are L3-BW bound -> halve bytes)
__global__ __launch_bounds__(256) void k_lin1(const float* __restrict__ x,
                                              const float* __restrict__ W1,
                                              const float* __restrict__ dinv,
                                              __half* __restrict__ lin) {
    __shared__ float sW[D_IN * D_HID];
    for (int t = threadIdx.x; t < D_IN * D_HID; t += 256) sW[t] = W1[t];
    __syncthreads();

    int g  = threadIdx.x & 3;
    int nl = threadIdx.x >> 2;
    int n  = blockIdx.x * 64 + nl;   // grid exact: 3125*64

    float acc[16];
#pragma unroll
    for (int j = 0; j < 16; ++j) acc[j] = 0.f;

    const float4* xr = (const float4*)(x + (size_t)n * D_IN + g * 32);
#pragma unroll
    for (int i = 0; i < 8; ++i) {
        float4 xv = xr[i];
        int k = g * 32 + i * 4;
#pragma unroll
        for (int j = 0; j < 16; ++j) {
            acc[j] += xv.x * sW[(k + 0) * 16 + j] + xv.y * sW[(k + 1) * 16 + j]
                    + xv.z * sW[(k + 2) * 16 + j] + xv.w * sW[(k + 3) * 16 + j];
        }
    }
#pragma unroll
    for (int j = 0; j < 16; ++j) {
        acc[j] += __shfl_xor(acc[j], 1);
        acc[j] += __shfl_xor(acc[j], 2);
    }
    float di = dinv[n];
    ushort4 pk;
    pk.x = __half_as_ushort(__float2half(acc[g * 4 + 0] * di));
    pk.y = __half_as_ushort(__float2half(acc[g * 4 + 1] * di));
    pk.z = __half_as_ushort(__float2half(acc[g * 4 + 2] * di));
    pk.w = __half_as_ushort(__float2half(acc[g * 4 + 3] * di));
    *(ushort4*)(lin + (size_t)n * 16 + g * 4) = pk;
}

// ---------------------------------------------------------------------------
// pull-gather, weight-folded, fp16 in / fp32 accum.
// MODE 1: v = relu(acc*dd + b1)*dd -> fp16 out.  MODE 0: v = acc*dd -> fp32 out.
template <int MODE>
__global__ __launch_bounds__(256) void k_gather(const int* __restrict__ rowptr,
                                                const int* __restrict__ col,
                                                const float* __restrict__ dinv,
                                                const __half* __restrict__ fin,
                                                const float* __restrict__ bias,
                                                void* __restrict__ outv) {
    int t = threadIdx.x;
    int n = blockIdx.x * 16 + (t >> 4);   // grid exact: 12500*16
    int lane = t & 15;
    int beg = rowptr[n], end = rowptr[n + 1];
    float a0 = __half2float(fin[n * 16 + lane]);   // self loop (pre-scaled)
    float a1 = 0.f, a2 = 0.f, a3 = 0.f, a4 = 0.f, a5 = 0.f, a6 = 0.f, a7 = 0.f;
    int i = beg;
    for (; i + 8 <= end; i += 8) {
        int s0 = col[i + 0], s1 = col[i + 1], s2 = col[i + 2], s3 = col[i + 3];
        int s4 = col[i + 4], s5 = col[i + 5], s6 = col[i + 6], s7 = col[i + 7];
        float f0 = __half2float(fin[s0 * 16 + lane]);
        float f1 = __half2float(fin[s1 * 16 + lane]);
        float f2 = __half2float(fin[s2 * 16 + lane]);
        float f3 = __half2float(fin[s3 * 16 + lane]);
        float f4 = __half2float(fin[s4 * 16 + lane]);
        float f5 = __half2float(fin[s5 * 16 + lane]);
        float f6 = __half2float(fin[s6 * 16 + lane]);
        float f7 = __half2float(fin[s7 * 16 + lane]);
        a0 += f0; a1 += f1; a2 += f2; a3 += f3;
        a4 += f4; a5 += f5; a6 += f6; a7 += f7;
    }
    for (; i < end; ++i) a0 += __half2float(fin[col[i] * 16 + lane]);
    float acc = ((a0 + a1) + (a2 + a3)) + ((a4 + a5) + (a6 + a7));
    float dd = dinv[n];
    float v = acc * dd;
    if (MODE) {
        v = fmaxf(v + bias[lane], 0.f) * dd;
        ((__half*)outv)[n * 16 + lane] = __float2half(v);
    } else {
        ((float*)outv)[n * 16 + lane] = v;
    }
}

// ---------------------------------------------------------------------------
// k_out v2: 64 nodes/block, 4 threads/node (43 classes each, c = q + 4i).
// Logits staged in LDS; epilogue = contiguous coalesced float4 copy-out.
__global__ __launch_bounds__(256) void k_out(const float* __restrict__ agg2,
                                             const float* __restrict__ W2,
                                             const float* __restrict__ b2,
                                             float* __restrict__ out) {
    __shared__ float sWt[D_OUT * D_HID];   // transposed [c][k], 11 KB
    __shared__ float sb[D_OUT];
    __shared__ float sl[64 * D_OUT];       // logits, 44 KB
    __shared__ float sls[64];              // per-node logsumexp
    int t = threadIdx.x;
    for (int m = t; m < D_OUT * D_HID; m += 256)
        sWt[m] = W2[(m & 15) * D_OUT + (m >> 4)];
    for (int m = t; m < D_OUT; m += 256) sb[m] = b2[m];
    __syncthreads();

    int nl = t >> 2, q = t & 3;
    int n  = blockIdx.x * 64 + nl;         // grid exact: 3125*64
    const float4* ar = (const float4*)(agg2 + (size_t)n * 16);
    float4 a0 = ar[0], a1 = ar[1], a2 = ar[2], a3 = ar[3];
    float a[16] = {a0.x, a0.y, a0.z, a0.w, a1.x, a1.y, a1.z, a1.w,
                   a2.x, a2.y, a2.z, a2.w, a3.x, a3.y, a3.z, a3.w};

    // phase A: 43 logits per thread -> LDS, track local max
    float mloc = -INFINITY;
    float* srow = sl + nl * D_OUT;
#pragma unroll 4
    for (int i = 0; i < 43; ++i) {
        int c = q + 4 * i;
        const float4* wr = (const float4*)(sWt + c * 16);
        float4 w0 = wr[0], w1 = wr[1], w2 = wr[2], w3 = wr[3];
        float l = sb[c];
        l += a[0]  * w0.x + a[1]  * w0.y + a[2]  * w0.z + a[3]  * w0.w;
        l += a[4]  * w1.x + a[5]  * w1.y + a[6]  * w1.z + a[7]  * w1.w;
        l += a[8]  * w2.x + a[9]  * w2.y + a[10] * w2.z + a[11] * w2.w;
        l += a[12] * w3.x + a[13] * w3.y + a[14] * w3.z + a[15] * w3.w;
        srow[c] = l;
        mloc = fmaxf(mloc, l);
    }
    // phase B: node max (2-step shfl over the 4 q-lanes), exp-sum, logsumexp
    mloc = fmaxf(mloc, __shfl_xor(mloc, 1));
    mloc = fmaxf(mloc, __shfl_xor(mloc, 2));
    float sloc = 0.f;
#pragma unroll 4
    for (int i = 0; i < 43; ++i) sloc += __expf(srow[q + 4 * i] - mloc);
    sloc += __shfl_xor(sloc, 1);
    sloc += __shfl_xor(sloc, 2);
    if (q == 0) sls[nl] = mloc + __logf(sloc);
    __syncthreads();

    // phase C: coalesced copy-out, subtracting per-node logsumexp
    const float4* sl4 = (const float4*)sl;
    float4* ob = (float4*)(out + (size_t)blockIdx.x * 64 * D_OUT);
    for (int jj = t; jj < 64 * D_OUT / 4; jj += 256) {   // 2752 float4s
        float4 v = sl4[jj];
        float ls = sls[jj / 43];                         // 43 float4s per node
        v.x -= ls; v.y -= ls; v.z -= ls; v.w -= ls;
        ob[jj] = v;
    }
}

// ---------------------------------------------------------------------------
extern "C" void kernel_launch(void* const* d_in, const int* in_sizes, int n_in,
                              void* d_out, int out_size, void* d_ws, size_t ws_size,
                              hipStream_t stream) {
    const float* x     = (const float*)d_in[0];
    const int*   edges = (const int*)d_in[1];   // [2, N_EDGES]
    const float* W1    = (const float*)d_in[2];
    const float* b1    = (const float*)d_in[3];
    const float* W2    = (const float*)d_in[4];
    const float* b2    = (const float*)d_in[5];
    float*       out   = (float*)d_out;

    const int* src = edges;
    const int* dst = edges + N_EDGES;

    unsigned* ws     = (unsigned*)d_ws;
    unsigned* btot   = ws + O_BTOT;
    unsigned* base   = ws + O_BASE;
    unsigned* counts = ws + O_CNT1;
    int*      rowptr = (int*)(ws + O_ROW);
    float*    dinv   = (float*)(ws + O_DINV);
    int*      col    = (int*)(ws + O_COL);
    unsigned* packed = ws + O_PACK;             // dead after k_csr
    __half*   f16a   = (__half*)(ws + O_F16A);  // lin1' (aliases packed)
    __half*   f16b   = (__half*)(ws + O_F16B);  // h'
    float*    agg2   = (float*)(ws + O_AGG2);

    // --- CSR build: zero global atomics, localized writes ---
    k_hist1    <<<NS1, 256, 0, stream>>>(dst, counts);
    k_scan_col <<<SBN, 256, 0, stream>>>(counts, btot);
    k_scan_base<<<1,    64, 0, stream>>>(btot, base);
    k_scatter1 <<<NS1, 256, 0, stream>>>(src, dst, counts, base, packed);
    k_csr      <<<SBN, 1024, 0, stream>>>(packed, base, rowptr, dinv, col);

    // --- layer 1: project 128->16 (pre-scaled, fp16), gather (relu fused) ---
    k_lin1     <<<N_NODES / 64, 256, 0, stream>>>(x, W1, dinv, f16a);
    k_gather<1><<<N_NODES / 16, 256, 0, stream>>>(rowptr, col, dinv, f16a, b1, f16b);

    // --- layer 2 (reassociated): gather h', then 16->172 + log_softmax ---
    k_gather<0><<<N_NODES / 16, 256, 0, stream>>>(rowptr, col, dinv, f16b, b1, agg2);
    k_out      <<<N_NODES / 64, 256, 0, stream>>>(agg2, W2, b2, out);
}